// Round 9
// baseline (767.604 us; speedup 1.0000x reference)
//
#include <hip/hip_runtime.h>

// Problem constants
#define NPTS   16384
#define IN_DIM 64
#define HID    128
#define KSEL   32

// Selection parameters (wave-private buffers, shared monotone thresholds)
#define CAP    128     // slots per (slice,row); proof: TRIG + 64 burst == CAP
#define TRIG   64      // compact when n > TRIG (checked once per fat iteration)
#define WIN_HI 48      // bisect early-exit window
#define SLACK  0.30f   // > 2x worst-case 2-term f16 d2 error (<=0.12 for |x|^2<=120)
#define INFBITS 0x7f800000u

typedef _Float16 f16x8 __attribute__((ext_vector_type(8)));
typedef float    f32x4 __attribute__((ext_vector_type(4)));
typedef unsigned short u16;
typedef unsigned int   u32;
typedef unsigned long long u64;

// ---------------------------------------------------------------------------
// Kernel A: prep — fp32 row sqnorm + f16 hi/lo split of x written in PACKED
// MFMA-fragment order: elem[ct*1024 + kh*512 + (g*16+li)*8 + j]
//                      = x[ct*16+li][kh*32+g*8+j]
// -> a wave reads a whole fragment as one coalesced 1KB load (lane*16B).
// ---------------------------------------------------------------------------
__global__ __launch_bounds__(256) void prep_kernel(const float* __restrict__ x,
                                                   float* __restrict__ sq,
                                                   u16* __restrict__ ph,
                                                   u16* __restrict__ pl) {
    const int i  = blockIdx.x * 256 + threadIdx.x;   // row
    const int ct = i >> 4, li = i & 15;
    const float4* xr = (const float4*)(x + (size_t)i * IN_DIM);
    float s = 0.f;
#pragma unroll
    for (int c = 0; c < 8; ++c) {                    // c = kh*4+g ; covers k=8c..8c+7
        float4 a = xr[2 * c], b = xr[2 * c + 1];
        float e[8] = {a.x, a.y, a.z, a.w, b.x, b.y, b.z, b.w};
        u32 hw[8], lw[8];
#pragma unroll
        for (int j = 0; j < 8; ++j) {
            s += e[j] * e[j];
            _Float16 h = (_Float16)e[j];
            float hf = (float)h;
            _Float16 l = (_Float16)(e[j] - hf);
            hw[j] = __builtin_bit_cast(u16, h);
            lw[j] = __builtin_bit_cast(u16, l);
        }
        size_t off = ((size_t)ct * 8 + c) * 128 + (size_t)li * 8;
        *(uint4*)(ph + off) = make_uint4(hw[0] | (hw[1] << 16), hw[2] | (hw[3] << 16),
                                         hw[4] | (hw[5] << 16), hw[6] | (hw[7] << 16));
        *(uint4*)(pl + off) = make_uint4(lw[0] | (lw[1] << 16), lw[2] | (lw[3] << 16),
                                         lw[4] | (lw[5] << 16), lw[6] | (lw[7] << 16));
    }
    sq[i] = s;
}

// ---------------------------------------------------------------------------
// Wave-local compaction of one row buffer (no barriers; slice-private).
// ---------------------------------------------------------------------------
__device__ __forceinline__ void compact_row(float* bdrow, u16* bjrow, int* pcnt,
                                            u32* pthr, int lane) {
    int n = *pcnt; n = n < CAP ? n : CAP;
    const float INF = __int_as_float(INFBITS);
    float dv0 = (lane      < n) ? bdrow[lane]      : INF;
    float dv1 = (lane + 64 < n) ? bdrow[lane + 64] : INF;
    u16   jv0 = (lane      < n) ? bjrow[lane]      : 0;
    u16   jv1 = (lane + 64 < n) ? bjrow[lane + 64] : 0;
    u32 u0 = __float_as_uint(dv0), u1 = __float_as_uint(dv1);
    u32 lo = 0, hi = *pthr, ans = hi;
    for (int it = 0; it < 26 && lo < hi; ++it) {
        u32 mid = lo + ((hi - lo) >> 1);
        int c = __popcll(__ballot(u0 <= mid)) + __popcll(__ballot(u1 <= mid));
        if (c < 32) lo = mid + 1;
        else { hi = mid; ans = mid; if (c <= WIN_HI) break; }
    }
    float ansf = __uint_as_float(ans) + SLACK;       // slack keeps true top-32
    u64 mlt = (1ull << lane) - 1ull;
    bool p0 = dv0 <= ansf;
    u64 b0 = __ballot(p0);
    if (p0) { int p = __popcll(b0 & mlt); bdrow[p] = dv0; bjrow[p] = jv0; }
    int base = __popcll(b0);
    bool p1 = dv1 <= ansf;
    u64 b1 = __ballot(p1);
    if (p1) { int p = base + __popcll(b1 & mlt); if (p < CAP) { bdrow[p] = dv1; bjrow[p] = jv1; } }
    base += __popcll(b1);
    if (lane == 0) {
        *pcnt = base < CAP ? base : CAP;
        atomicMin(pthr, __float_as_uint(ansf));      // shared, monotone
    }
}

// ---------------------------------------------------------------------------
// Kernel B: barrier-free MFMA kNN, FAT iterations.
// Grid 1024 blocks, block = 256 thr = 4 waves, 16 query rows per block.
// Wave s: iteration i covers coltiles 16*i + s*4 + {0..3} (64 cols/iter,
// 64 iterations). Per iter: 8 coalesced 1KB fragment loads (prefetched one
// iter ahead), 16 MFMA f16 (4 independent 4-chains), __any-guarded inserts
// into wave-private buffers, ONE compact-check ballot. Thresholds shared
// across slices via atomicMin (monotone -> stale reads safe). One
// __syncthreads, then merge: exact fp32 re-verify (<=512 cands/row) +
// bisect-set top-32 (unordered; pooling is a mean).
// ---------------------------------------------------------------------------
__global__ __launch_bounds__(256, 3) void knn_kernel(const float* __restrict__ x,
                                                     const u16* __restrict__ ph,
                                                     const u16* __restrict__ pl,
                                                     const float* __restrict__ sq,
                                                     int* __restrict__ graph) {
    __shared__ float bd[4][16][CAP];     // 32 KB
    __shared__ u16   bj[4][16][CAP];     // 16 KB
    __shared__ int   bcnt[4][16];
    __shared__ u32   bthrU[16];          // shared across slices (atomicMin)

    const int t = threadIdx.x, lane = t & 63, wave = t >> 6;
    const int g = lane >> 4, li = lane & 15;
    const int rg = blockIdx.x;           // rowgroup: rows rg*16..+15
    const int rbase = rg * 16;

    if (t < 64) bcnt[t >> 4][t & 15] = 0;
    if (t < 16) bthrU[t] = INFBITS;

    // A fragments (hi+lo) for this block's 16 rows, from the packed array.
    f16x8 ah[2], al[2];
#pragma unroll
    for (int kh = 0; kh < 2; ++kh) {
        size_t o = ((size_t)rg * 2 + kh) * 512 + (size_t)lane * 8;
        ah[kh] = *(const f16x8*)(ph + o);
        al[kh] = *(const f16x8*)(pl + o);
    }
    float sar[4];
#pragma unroll
    for (int r = 0; r < 4; ++r) sar[r] = sq[rbase + g * 4 + r];
    __syncthreads();                     // covers bcnt/bthrU init

    // load first coltile group (4 coltiles)
    int ctb = wave * 4;
    f16x8 cb[4][2]; float csb[4];
#pragma unroll
    for (int c = 0; c < 4; ++c) {
        size_t o = (size_t)(ctb + c) * 1024 + (size_t)lane * 8;
        cb[c][0] = *(const f16x8*)(ph + o);
        cb[c][1] = *(const f16x8*)(ph + o + 512);
        csb[c] = sq[(ctb + c) * 16 + li];
    }

    for (int i = 0; i < 64; ++i) {
        const int nctb = ctb + 16;
        f16x8 nb[4][2]; float nsb[4];
        if (i < 63) {                    // prefetch next group (uniform branch)
#pragma unroll
            for (int c = 0; c < 4; ++c) {
                size_t o = (size_t)(nctb + c) * 1024 + (size_t)lane * 8;
                nb[c][0] = *(const f16x8*)(ph + o);
                nb[c][1] = *(const f16x8*)(ph + o + 512);
                nsb[c] = sq[(nctb + c) * 16 + li];
            }
        }
        // 16 MFMA: 4 independent chains (2-term split: (ah+al).bh)
        f32x4 acc[4];
#pragma unroll
        for (int c = 0; c < 4; ++c) {
            f32x4 a = {0.f, 0.f, 0.f, 0.f};
            a = __builtin_amdgcn_mfma_f32_16x16x32_f16(ah[0], cb[c][0], a, 0, 0, 0);
            a = __builtin_amdgcn_mfma_f32_16x16x32_f16(ah[1], cb[c][1], a, 0, 0, 0);
            a = __builtin_amdgcn_mfma_f32_16x16x32_f16(al[0], cb[c][0], a, 0, 0, 0);
            a = __builtin_amdgcn_mfma_f32_16x16x32_f16(al[1], cb[c][1], a, 0, 0, 0);
            acc[c] = a;
        }
        // epilogue: one threshold read per iteration (stale-safe: monotone)
        uint4 tu = *(const uint4*)&bthrU[g * 4];
        const float thr[4] = {__uint_as_float(tu.x), __uint_as_float(tu.y),
                              __uint_as_float(tu.z), __uint_as_float(tu.w)};
#pragma unroll
        for (int c = 0; c < 4; ++c) {
#pragma unroll
            for (int r = 0; r < 4; ++r) {
                float d = fmaf(-2.f, acc[c][r], sar[r] + csb[c]);
                bool pred = d <= thr[r];
                if (__any(pred)) {       // skip DS ops entirely when none pass
                    if (pred) {
                        int row = g * 4 + r;
                        int pos = atomicAdd(&bcnt[wave][row], 1);
                        if (pos < CAP) {
                            bd[wave][row][pos] = fmaxf(d, 0.f);  // monotone bits
                            bj[wave][row][pos] = (u16)((ctb + c) * 16 + li);
                        }
                    }
                }
            }
        }
        // ONE compact-check per fat iteration
        u64 need = __ballot((lane < 16) && (bcnt[wave][lane] > TRIG));
        while (need) {
            int rr = __ffsll((long long)need) - 1;
            need &= need - 1;
            compact_row(bd[wave][rr], bj[wave][rr], &bcnt[wave][rr], &bthrU[rr], lane);
        }
        ctb = nctb;
#pragma unroll
        for (int c = 0; c < 4; ++c) { cb[c][0] = nb[c][0]; cb[c][1] = nb[c][1]; csb[c] = nsb[c]; }
    }

    __syncthreads();   // the only cross-wave sync: slices' buffers final

    // Merge: wave w handles rows w*4..w*4+3. Exact fp32 re-verify of all
    // slices' candidates (8 segments, empty ones skipped uniformly), then
    // bisect-set top-32 (order-free).
    const u64 mlt = (1ull << lane) - 1ull;
    for (int ii = 0; ii < 4; ++ii) {
        const int lr = wave * 4 + ii;
        const int gr = rbase + lr;
        const float sqa = sq[gr];
        const float4* xa = (const float4*)(x + (size_t)gr * IN_DIM);
        int ns[4];
#pragma unroll
        for (int s = 0; s < 4; ++s) { int v = bcnt[s][lr]; ns[s] = v < CAP ? v : CAP; }
        u32 db[8]; int jj[8];
#pragma unroll
        for (int s8 = 0; s8 < 8; ++s8) {
            const int sl = s8 >> 1;
            const int half = s8 & 1;
            u32 dbits = INFBITS; int j = 0;
            if (ns[sl] > half * 64) {            // uniform skip of empty segment
                int idx = half * 64 + lane;
                if (idx < ns[sl]) {
                    j = bj[sl][lr][idx];
                    const float4* xb = (const float4*)(x + (size_t)j * IN_DIM);
                    float dot = 0.f;
#pragma unroll
                    for (int q = 0; q < 16; ++q) {
                        float4 a = xa[q], b = xb[q];
                        dot += a.x * b.x + a.y * b.y + a.z * b.z + a.w * b.w;
                    }
                    float d = fmaxf(fmaf(-2.f, dot, sqa + sq[j]), 0.f);
                    dbits = __float_as_uint(d);
                }
            }
            db[s8] = dbits; jj[s8] = j;
        }
        // bisect minimal ans with count(<=ans) >= 32
        u32 lo = 0, hi = INFBITS, ans = hi;
        for (int it = 0; it < 32 && lo < hi; ++it) {
            u32 mid = lo + ((hi - lo) >> 1);
            int c = 0;
#pragma unroll
            for (int s8 = 0; s8 < 8; ++s8)
                c += __popcll(__ballot(db[s8] <= mid));
            if (c < 32) lo = mid + 1;
            else { hi = mid; ans = mid; if (c == 32) break; }
        }
        // tie handling: keep d<ans plus lowest-index ties to fill exactly 32
        bool tie[8]; int c_le = 0;
#pragma unroll
        for (int s8 = 0; s8 < 8; ++s8) {
            tie[s8] = (db[s8] == ans);
            c_le += __popcll(__ballot(db[s8] <= ans));
        }
        int extra = c_le - 32;                  // ties beyond need
        while (extra > 0) {                     // rare: drop largest-j ties
            int mx = -1;
#pragma unroll
            for (int s8 = 0; s8 < 8; ++s8) if (tie[s8] && jj[s8] > mx) mx = jj[s8];
#pragma unroll
            for (int off = 32; off > 0; off >>= 1) {
                int o = __shfl_xor(mx, off); mx = mx > o ? mx : o;
            }
#pragma unroll
            for (int s8 = 0; s8 < 8; ++s8) if (tie[s8] && jj[s8] == mx) tie[s8] = false;
            --extra;
        }
        int* gp = graph + (size_t)gr * KSEL;
        int base = 0;
#pragma unroll
        for (int s8 = 0; s8 < 8; ++s8) {
            bool k = (db[s8] < ans) || tie[s8];
            u64 b = __ballot(k);
            if (k) gp[base + __popcll(b & mlt)] = jj[s8];
            base += __popcll(b);
        }
    }
}

// ---------------------------------------------------------------------------
// Kernel C: XWa[i][h]=x_i.w[h][0:64], XWb[i][h]=x_i.w[h][64:128],
//           OUTB[i][o]=x_i.w2[o][128:192] (direct to d_out).
// ---------------------------------------------------------------------------
__global__ __launch_bounds__(384) void xw_kernel(const float* __restrict__ x,
                                                 const float* __restrict__ w,
                                                 const float* __restrict__ w2,
                                                 float* __restrict__ XWa,
                                                 float* __restrict__ XWb,
                                                 float* __restrict__ outb) {
    __shared__ float xs[64][64];
    const int t = threadIdx.x;
    const int rbase = blockIdx.x * 64;

    for (int idx = t; idx < 64 * 16; idx += 384) {
        int r = idx >> 4, q = idx & 15;
        ((float4*)xs[r])[q] = ((const float4*)(x + (size_t)(rbase + r) * IN_DIM))[q];
    }
    const int kind = t >> 7;
    const int idx  = t & 127;
    const float* wp = (kind == 0) ? (w + (size_t)idx * 128)
                    : (kind == 1) ? (w + (size_t)idx * 128 + 64)
                                  : (w2 + (size_t)idx * 192 + 128);
    float4 wreg[16];
#pragma unroll
    for (int q = 0; q < 16; ++q) wreg[q] = ((const float4*)wp)[q];
    __syncthreads();

    for (int r = 0; r < 64; ++r) {
        float acc = 0.f;
#pragma unroll
        for (int q = 0; q < 16; ++q) {
            float4 xv = ((float4*)xs[r])[q];
            acc += xv.x * wreg[q].x + xv.y * wreg[q].y +
                   xv.z * wreg[q].z + xv.w * wreg[q].w;
        }
        size_t o = (size_t)(rbase + r) * 128 + idx;
        if (kind == 0)      XWa[o]  = acc;
        else if (kind == 1) XWb[o]  = acc;
        else                outb[o] = acc;
    }
}

// ---------------------------------------------------------------------------
// Kernel D: pooled[i][h] = mean_c clip(XWa[g[i][c]][h] + XWb[i][h], -1, 1)
// One wave per row: shfl-broadcast neighbor index -> coalesced 512B gathers.
// ---------------------------------------------------------------------------
__global__ __launch_bounds__(256) void pool_kernel(const int* __restrict__ graph,
                                                   const float* __restrict__ XWa,
                                                   const float* __restrict__ XWb,
                                                   float* __restrict__ pooled) {
    const int t = threadIdx.x, lane = t & 63, wave = t >> 6;
    const int row = blockIdx.x * 4 + wave;
    int gi = graph[(size_t)row * KSEL + (lane & 31)];
    float2 b = ((const float2*)(XWb + (size_t)row * HID))[lane];
    float2 acc = {0.f, 0.f};
#pragma unroll
    for (int c = 0; c < KSEL; ++c) {
        int j = __shfl(gi, c);
        float2 v = ((const float2*)(XWa + (size_t)j * HID))[lane];
        acc.x += fminf(fmaxf(v.x + b.x, -1.f), 1.f);
        acc.y += fminf(fmaxf(v.y + b.y, -1.f), 1.f);
    }
    float2* pr = (float2*)(pooled + (size_t)row * HID);
    pr[lane] = make_float2(acc.x * (1.f / 32.f), acc.y * (1.f / 32.f));
}

// ---------------------------------------------------------------------------
// Kernel E: out[i][o] += pooled[i] . w2[o][0:128]  (out holds OUTB)
// ---------------------------------------------------------------------------
__global__ __launch_bounds__(256) void out_kernel(const float* __restrict__ pooled,
                                                  const float* __restrict__ w2,
                                                  float* __restrict__ out) {
    __shared__ float ws2[128][132];
    __shared__ float pt[64][128];
    const int t = threadIdx.x;
    const int rbase = blockIdx.x * 64;

    for (int idx = t; idx < 128 * 32; idx += 256) {
        int o = idx >> 5, q = idx & 31;
        ((float4*)&ws2[o][0])[q] = ((const float4*)(w2 + (size_t)o * 192))[q];
    }
    for (int idx = t; idx < 64 * 32; idx += 256) {
        int r = idx >> 5, q = idx & 31;
        ((float4*)&pt[r][0])[q] = ((const float4*)(pooled + (size_t)(rbase + r) * 128))[q];
    }
    __syncthreads();

    const int o = t & 127, rsub = t >> 7;
    for (int rp = 0; rp < 32; ++rp) {
        int r = rp * 2 + rsub;
        float acc = 0.f;
#pragma unroll
        for (int q = 0; q < 32; ++q) {
            float4 pv = ((float4*)&pt[r][0])[q];
            float4 wv = ((float4*)&ws2[o][0])[q];
            acc += pv.x * wv.x + pv.y * wv.y + pv.z * wv.z + pv.w * wv.w;
        }
        size_t off = (size_t)(rbase + r) * 128 + o;
        out[off] += acc;
    }
}

// ---------------------------------------------------------------------------
extern "C" void kernel_launch(void* const* d_in, const int* in_sizes, int n_in,
                              void* d_out, int out_size, void* d_ws, size_t ws_size,
                              hipStream_t stream) {
    const float* x  = (const float*)d_in[0];   // (16384, 64)
    const float* w  = (const float*)d_in[1];   // (128, 128)
    const float* w2 = (const float*)d_in[2];   // (128, 192)
    float* out = (float*)d_out;                // (16384, 128)

    // workspace (26.07 MB): pooled aliases ph/pl (pool runs after knn)
    float* sq     = (float*)d_ws;                           // 64 KB
    int*   graph  = (int*)(sq + NPTS);                      // 2 MB
    float* XWa    = (float*)(graph + (size_t)NPTS * KSEL);  // 8 MB
    float* XWb    = XWa + (size_t)NPTS * HID;               // 8 MB
    float* region = XWb + (size_t)NPTS * HID;               // 8 MB
    u16*   ph     = (u16*)region;                           // 2 MB (packed f16 hi)
    u16*   pl     = ph + (size_t)NPTS * IN_DIM;             // 2 MB (packed f16 lo)
    float* pooled = region;                                 // aliases ph/pl

    prep_kernel<<<NPTS / 256, 256, 0, stream>>>(x, sq, ph, pl);
    knn_kernel<<<NPTS / 16, 256, 0, stream>>>(x, ph, pl, sq, graph);
    xw_kernel<<<NPTS / 64, 384, 0, stream>>>(x, w, w2, XWa, XWb, out);
    pool_kernel<<<NPTS / 4, 256, 0, stream>>>(graph, XWa, XWb, pooled);
    out_kernel<<<NPTS / 64, 256, 0, stream>>>(pooled, w2, out);
}

// Round 11
// 761.704 us; speedup vs baseline: 1.0077x; 1.0077x over previous
//
#include <hip/hip_runtime.h>

// Problem constants
#define NPTS   16384
#define IN_DIM 64
#define HID    128
#define KSEL   32

// Selection parameters: packed u32 keys = (dfix18 << 14) | col14
#define CAP      64       // slots per (slice,row); proof: TRIG + 16 burst == CAP
#define TRIG     48       // compact when n > TRIG (checked every iteration)
#define WIN_HI   44       // bisect early-exit when count <= this
#define SLACK_FIX 160u    // 0.3125 in d units (x512); covers 2x split err + quant
#define DMAX_FIX 0x3FFFFu // 18-bit d field max

typedef _Float16 f16x8 __attribute__((ext_vector_type(8)));
typedef float    f32x4 __attribute__((ext_vector_type(4)));
typedef unsigned short u16;
typedef unsigned int   u32;
typedef unsigned long long u64;
#define INFBITS 0x7f800000u

// ---------------------------------------------------------------------------
// Kernel A: prep — fp32 row sqnorm + f16 hi/lo split of x written in PACKED
// MFMA-fragment order: elem[ct*1024 + kh*512 + lane*8 + j] = x[ct*16+li][kh*32+g*8+j]
// (lane = g*16+li) -> a wave reads a fragment as one coalesced 1KB load.
// ---------------------------------------------------------------------------
__global__ __launch_bounds__(256) void prep_kernel(const float* __restrict__ x,
                                                   float* __restrict__ sq,
                                                   u16* __restrict__ ph,
                                                   u16* __restrict__ pl) {
    const int i  = blockIdx.x * 256 + threadIdx.x;   // row
    const int ct = i >> 4, li = i & 15;
    const float4* xr = (const float4*)(x + (size_t)i * IN_DIM);
    float s = 0.f;
#pragma unroll
    for (int c = 0; c < 8; ++c) {                    // c = kh*4+g ; covers k=8c..8c+7
        float4 a = xr[2 * c], b = xr[2 * c + 1];
        float e[8] = {a.x, a.y, a.z, a.w, b.x, b.y, b.z, b.w};
        u32 hw[8], lw[8];
#pragma unroll
        for (int j = 0; j < 8; ++j) {
            s += e[j] * e[j];
            _Float16 h = (_Float16)e[j];
            float hf = (float)h;
            _Float16 l = (_Float16)(e[j] - hf);
            hw[j] = __builtin_bit_cast(u16, h);
            lw[j] = __builtin_bit_cast(u16, l);
        }
        size_t off = ((size_t)ct * 8 + c) * 128 + (size_t)li * 8;
        *(uint4*)(ph + off) = make_uint4(hw[0] | (hw[1] << 16), hw[2] | (hw[3] << 16),
                                         hw[4] | (hw[5] << 16), hw[6] | (hw[7] << 16));
        *(uint4*)(pl + off) = make_uint4(lw[0] | (lw[1] << 16), lw[2] | (lw[3] << 16),
                                         lw[4] | (lw[5] << 16), lw[6] | (lw[7] << 16));
    }
    sq[i] = s;
}

// ---------------------------------------------------------------------------
// Kernel B: barrier-free MFMA kNN, 8 slices, packed keys, full occupancy.
// Grid 1024 blocks x 512 thr (8 waves). Block owns 16 query rows; wave s
// covers coltiles s + 8*i (i<128). Per slim iteration: 2 coalesced 1KB
// fragment loads (1-deep prefetch), 4 MFMA f16 (2-term split), key pack,
// __any-guarded insert into wave-private CAP-64 buffer, compact-check.
// Thresholds (packed-key space) shared across 8 slices via LDS atomicMin
// (monotone -> stale reads safe). One __syncthreads, then merge: exact fp32
// re-verify (8 segments of 64) + bisect-set top-32 (unordered; pool = mean).
// __launch_bounds__(512,8): 4 blocks/CU x 8 waves = 32 waves/CU, VGPR<=64.
// ---------------------------------------------------------------------------
__global__ __launch_bounds__(512, 8) void knn_kernel(const float* __restrict__ x,
                                                     const u16* __restrict__ ph,
                                                     const u16* __restrict__ pl,
                                                     const float* __restrict__ sq,
                                                     int* __restrict__ graph) {
    __shared__ u32 cand[8][16][CAP];     // 32 KB packed keys
    __shared__ int bcnt[8][16];          // 512 B
    __shared__ u32 bthrU[16];            // packed-key thresholds (atomicMin)

    const int t = threadIdx.x, lane = t & 63, wave = t >> 6;   // wave 0..7
    const int g = lane >> 4, li = lane & 15;
    const int rg = blockIdx.x;           // rowgroup: rows rg*16..+15
    const int rbase = rg * 16;

    if (t < 128) bcnt[t >> 4][t & 15] = 0;
    if (t < 16)  bthrU[t] = 0xffffffffu;

    // A fragments (hi+lo) for this block's 16 rows (same for all 8 waves).
    f16x8 ah[2], al[2];
#pragma unroll
    for (int kh = 0; kh < 2; ++kh) {
        size_t o = ((size_t)rg * 2 + kh) * 512 + (size_t)lane * 8;
        ah[kh] = *(const f16x8*)(ph + o);
        al[kh] = *(const f16x8*)(pl + o);
    }
    float sar[4];
#pragma unroll
    for (int r = 0; r < 4; ++r) sar[r] = sq[rbase + g * 4 + r];
    __syncthreads();                     // covers bcnt/bthrU init

    // first coltile of this wave's slice
    int ct = wave;
    f16x8 cb0, cb1; float csb;
    {
        size_t o = (size_t)ct * 1024 + (size_t)lane * 8;
        cb0 = *(const f16x8*)(ph + o);
        cb1 = *(const f16x8*)(ph + o + 512);
        csb = sq[ct * 16 + li];
    }

    for (int i = 0; i < 128; ++i) {
        const int nct = ct + 8;
        f16x8 nb0, nb1; float nsb = 0.f;
        if (i < 127) {                   // 1-deep prefetch (uniform branch)
            size_t o = (size_t)nct * 1024 + (size_t)lane * 8;
            nb0 = *(const f16x8*)(ph + o);
            nb1 = *(const f16x8*)(ph + o + 512);
            nsb = sq[nct * 16 + li];
        }
        // 2-term split dot: (ah+al).bh  (4 MFMA)
        f32x4 a = {0.f, 0.f, 0.f, 0.f};
        a = __builtin_amdgcn_mfma_f32_16x16x32_f16(ah[0], cb0, a, 0, 0, 0);
        a = __builtin_amdgcn_mfma_f32_16x16x32_f16(ah[1], cb1, a, 0, 0, 0);
        a = __builtin_amdgcn_mfma_f32_16x16x32_f16(al[0], cb0, a, 0, 0, 0);
        a = __builtin_amdgcn_mfma_f32_16x16x32_f16(al[1], cb1, a, 0, 0, 0);

        // epilogue: pack key, filter vs shared thresholds (stale-safe)
        uint4 tu = *(const uint4*)&bthrU[g * 4];
        const u32 thrk[4] = {tu.x, tu.y, tu.z, tu.w};
        const u32 colid = (u32)(ct * 16 + li);
#pragma unroll
        for (int r = 0; r < 4; ++r) {
            float d = fmaxf(fmaf(-2.f, a[r], sar[r] + csb), 0.f);
            u32 dfix = (u32)fminf(d * 512.0f, 262143.0f);
            u32 key = (dfix << 14) | colid;
            bool pred = key <= thrk[r];
            if (__any(pred)) {           // skip DS ops when no lane passes
                if (pred) {
                    int row = g * 4 + r;
                    int pos = atomicAdd(&bcnt[wave][row], 1);
                    if (pos < CAP) cand[wave][row][pos] = key;
                }
            }
        }
        // compact-check: burst<=16/row/iter, TRIG+16==CAP -> no silent loss
        u64 need = __ballot((lane < 16) && (bcnt[wave][lane] > TRIG));
        while (need) {                   // wave-uniform
            int rr = __ffsll((long long)need) - 1;
            need &= need - 1;
            int n = bcnt[wave][rr]; n = n < CAP ? n : CAP;
            u32 k0 = (lane < n) ? cand[wave][rr][lane] : 0xffffffffu;
            u32 d0 = k0 >> 14;
            u32 lo = 0, hi = bthrU[rr] >> 14, ans = hi;
            for (int it = 0; it < 18 && lo < hi; ++it) {
                u32 mid = lo + ((hi - lo) >> 1);
                int c = __popcll(__ballot(d0 <= mid));
                if (c < 32) lo = mid + 1;
                else { hi = mid; ans = mid; if (c <= WIN_HI) break; }
            }
            u32 ansd = ans + SLACK_FIX; ansd = ansd < DMAX_FIX ? ansd : DMAX_FIX;
            bool keep = d0 <= ansd;      // slack band keeps true top-32
            u64 bal = __ballot(keep);
            int pos = __popcll(bal & ((1ull << lane) - 1ull));
            if (keep) cand[wave][rr][pos] = k0;      // pos < 64 always
            if (lane == 0) {
                bcnt[wave][rr] = __popcll(bal);
                atomicMin(&bthrU[rr], (ansd << 14) | 0x3fffu);
            }
        }
        ct = nct; cb0 = nb0; cb1 = nb1; csb = nsb;
    }

    __syncthreads();   // the only cross-wave sync: all slice buffers final

    // Merge: wave w handles rows 2w, 2w+1. Exact fp32 re-verify of the 8
    // slices' candidates (8 segments of 64), then bisect-set top-32.
    const u64 mlt = (1ull << lane) - 1ull;
    for (int ii = 0; ii < 2; ++ii) {
        const int lr = wave * 2 + ii;
        const int gr = rbase + lr;
        const float sqa = sq[gr];
        const float4* xa = (const float4*)(x + (size_t)gr * IN_DIM);
        u32 db[8]; int jj[8];
#pragma unroll
        for (int s8 = 0; s8 < 8; ++s8) {
            int nsl = bcnt[s8][lr]; nsl = nsl < CAP ? nsl : CAP;
            u32 dbits = INFBITS; int j = 0;
            if (nsl > 0) {               // uniform skip of empty segment
                if (lane < nsl) {
                    j = (int)(cand[s8][lr][lane] & 0x3fffu);
                    const float4* xb = (const float4*)(x + (size_t)j * IN_DIM);
                    float dot = 0.f;
#pragma unroll
                    for (int q = 0; q < 16; ++q) {
                        float4 av = xa[q], bv = xb[q];
                        dot += av.x * bv.x + av.y * bv.y + av.z * bv.z + av.w * bv.w;
                    }
                    float d = fmaxf(fmaf(-2.f, dot, sqa + sq[j]), 0.f);
                    dbits = __float_as_uint(d);
                }
            }
            db[s8] = dbits; jj[s8] = j;
        }
        // bisect minimal ans with count(<=ans) >= 32  (exact fp32 bits)
        u32 lo = 0, hi = INFBITS, ans = hi;
        for (int it = 0; it < 32 && lo < hi; ++it) {
            u32 mid = lo + ((hi - lo) >> 1);
            int c = 0;
#pragma unroll
            for (int s8 = 0; s8 < 8; ++s8)
                c += __popcll(__ballot(db[s8] <= mid));
            if (c < 32) lo = mid + 1;
            else { hi = mid; ans = mid; if (c == 32) break; }
        }
        // tie handling: keep d<ans plus lowest-index ties to fill exactly 32
        bool tie[8]; int c_le = 0;
#pragma unroll
        for (int s8 = 0; s8 < 8; ++s8) {
            tie[s8] = (db[s8] == ans);
            c_le += __popcll(__ballot(db[s8] <= ans));
        }
        int extra = c_le - 32;           // ties beyond need
        while (extra > 0) {              // rare: drop largest-j ties
            int mx = -1;
#pragma unroll
            for (int s8 = 0; s8 < 8; ++s8) if (tie[s8] && jj[s8] > mx) mx = jj[s8];
#pragma unroll
            for (int off = 32; off > 0; off >>= 1) {
                int o = __shfl_xor(mx, off); mx = mx > o ? mx : o;
            }
#pragma unroll
            for (int s8 = 0; s8 < 8; ++s8) if (tie[s8] && jj[s8] == mx) tie[s8] = false;
            --extra;
        }
        int* gp = graph + (size_t)gr * KSEL;
        int base = 0;
#pragma unroll
        for (int s8 = 0; s8 < 8; ++s8) {
            bool k = (db[s8] < ans) || tie[s8];
            u64 b = __ballot(k);
            if (k) gp[base + __popcll(b & mlt)] = jj[s8];
            base += __popcll(b);
        }
    }
}

// ---------------------------------------------------------------------------
// Kernel C: XWa[i][h]=x_i.w[h][0:64], XWb[i][h]=x_i.w[h][64:128],
//           OUTB[i][o]=x_i.w2[o][128:192] (direct to d_out).
// ---------------------------------------------------------------------------
__global__ __launch_bounds__(384) void xw_kernel(const float* __restrict__ x,
                                                 const float* __restrict__ w,
                                                 const float* __restrict__ w2,
                                                 float* __restrict__ XWa,
                                                 float* __restrict__ XWb,
                                                 float* __restrict__ outb) {
    __shared__ float xs[64][64];
    const int t = threadIdx.x;
    const int rbase = blockIdx.x * 64;

    for (int idx = t; idx < 64 * 16; idx += 384) {
        int r = idx >> 4, q = idx & 15;
        ((float4*)xs[r])[q] = ((const float4*)(x + (size_t)(rbase + r) * IN_DIM))[q];
    }
    const int kind = t >> 7;
    const int idx  = t & 127;
    const float* wp = (kind == 0) ? (w + (size_t)idx * 128)
                    : (kind == 1) ? (w + (size_t)idx * 128 + 64)
                                  : (w2 + (size_t)idx * 192 + 128);
    float4 wreg[16];
#pragma unroll
    for (int q = 0; q < 16; ++q) wreg[q] = ((const float4*)wp)[q];
    __syncthreads();

    for (int r = 0; r < 64; ++r) {
        float acc = 0.f;
#pragma unroll
        for (int q = 0; q < 16; ++q) {
            float4 xv = ((float4*)xs[r])[q];
            acc += xv.x * wreg[q].x + xv.y * wreg[q].y +
                   xv.z * wreg[q].z + xv.w * wreg[q].w;
        }
        size_t o = (size_t)(rbase + r) * 128 + idx;
        if (kind == 0)      XWa[o]  = acc;
        else if (kind == 1) XWb[o]  = acc;
        else                outb[o] = acc;
    }
}

// ---------------------------------------------------------------------------
// Kernel D: pooled[i][h] = mean_c clip(XWa[g[i][c]][h] + XWb[i][h], -1, 1)
// One wave per row: shfl-broadcast neighbor index -> coalesced 512B gathers.
// ---------------------------------------------------------------------------
__global__ __launch_bounds__(256) void pool_kernel(const int* __restrict__ graph,
                                                   const float* __restrict__ XWa,
                                                   const float* __restrict__ XWb,
                                                   float* __restrict__ pooled) {
    const int t = threadIdx.x, lane = t & 63, wave = t >> 6;
    const int row = blockIdx.x * 4 + wave;
    int gi = graph[(size_t)row * KSEL + (lane & 31)];
    float2 b = ((const float2*)(XWb + (size_t)row * HID))[lane];
    float2 acc = {0.f, 0.f};
#pragma unroll
    for (int c = 0; c < KSEL; ++c) {
        int j = __shfl(gi, c);
        float2 v = ((const float2*)(XWa + (size_t)j * HID))[lane];
        acc.x += fminf(fmaxf(v.x + b.x, -1.f), 1.f);
        acc.y += fminf(fmaxf(v.y + b.y, -1.f), 1.f);
    }
    float2* pr = (float2*)(pooled + (size_t)row * HID);
    pr[lane] = make_float2(acc.x * (1.f / 32.f), acc.y * (1.f / 32.f));
}

// ---------------------------------------------------------------------------
// Kernel E: out[i][o] += pooled[i] . w2[o][0:128]  (out holds OUTB)
// ---------------------------------------------------------------------------
__global__ __launch_bounds__(256) void out_kernel(const float* __restrict__ pooled,
                                                  const float* __restrict__ w2,
                                                  float* __restrict__ out) {
    __shared__ float ws2[128][132];
    __shared__ float pt[64][128];
    const int t = threadIdx.x;
    const int rbase = blockIdx.x * 64;

    for (int idx = t; idx < 128 * 32; idx += 256) {
        int o = idx >> 5, q = idx & 31;
        ((float4*)&ws2[o][0])[q] = ((const float4*)(w2 + (size_t)o * 192))[q];
    }
    for (int idx = t; idx < 64 * 32; idx += 256) {
        int r = idx >> 5, q = idx & 31;
        ((float4*)&pt[r][0])[q] = ((const float4*)(pooled + (size_t)(rbase + r) * 128))[q];
    }
    __syncthreads();

    const int o = t & 127, rsub = t >> 7;
    for (int rp = 0; rp < 32; ++rp) {
        int r = rp * 2 + rsub;
        float acc = 0.f;
#pragma unroll
        for (int q = 0; q < 32; ++q) {
            float4 pv = ((float4*)&pt[r][0])[q];
            float4 wv = ((float4*)&ws2[o][0])[q];
            acc += pv.x * wv.x + pv.y * wv.y + pv.z * wv.z + pv.w * wv.w;
        }
        size_t off = (size_t)(rbase + r) * 128 + o;
        out[off] += acc;
    }
}

// ---------------------------------------------------------------------------
extern "C" void kernel_launch(void* const* d_in, const int* in_sizes, int n_in,
                              void* d_out, int out_size, void* d_ws, size_t ws_size,
                              hipStream_t stream) {
    const float* x  = (const float*)d_in[0];   // (16384, 64)
    const float* w  = (const float*)d_in[1];   // (128, 128)
    const float* w2 = (const float*)d_in[2];   // (128, 192)
    float* out = (float*)d_out;                // (16384, 128)

    // workspace (26.07 MB): pooled aliases ph/pl (pool runs after knn)
    float* sq     = (float*)d_ws;                           // 64 KB
    int*   graph  = (int*)(sq + NPTS);                      // 2 MB
    float* XWa    = (float*)(graph + (size_t)NPTS * KSEL);  // 8 MB
    float* XWb    = XWa + (size_t)NPTS * HID;               // 8 MB
    float* region = XWb + (size_t)NPTS * HID;               // 8 MB
    u16*   ph     = (u16*)region;                           // 2 MB (packed f16 hi)
    u16*   pl     = ph + (size_t)NPTS * IN_DIM;             // 2 MB (packed f16 lo)
    float* pooled = region;                                 // aliases ph/pl

    prep_kernel<<<NPTS / 256, 256, 0, stream>>>(x, sq, ph, pl);
    knn_kernel<<<NPTS / 16, 512, 0, stream>>>(x, ph, pl, sq, graph);
    xw_kernel<<<NPTS / 64, 384, 0, stream>>>(x, w, w2, XWa, XWb, out);
    pool_kernel<<<NPTS / 4, 256, 0, stream>>>(graph, XWa, XWb, pooled);
    out_kernel<<<NPTS / 64, 256, 0, stream>>>(pooled, w2, out);
}